// Round 1
// baseline (235.265 us; speedup 1.0000x reference)
//
#include <hip/hip_runtime.h>

// ChunkEmbedding: embedding gather + normalized weighted pooling per chunk,
// ragged scatter into [B, T, D] with CLS/SEP rows + mask.
//
// Shapes (from setup_inputs): N=4096 chunks, L=64 tokens, D=768, B=32, T=145.
// Derived on host: N = in_sizes[0]/64, B*T = out_size/769. B read on device.

constexpr int CHUNK_LEN = 64;
constexpr int DIM       = 768;
constexpr int D4        = DIM / 4;   // 192 float4 lanes per row
constexpr int CLS_IDX   = 101;
constexpr int SEP_IDX   = 102;
constexpr int MAX_B     = 256;       // guard blocks for sample work

__global__ __launch_bounds__(D4)
void chunk_embed_kernel(const int*   __restrict__ input_ids,   // [N, 64]
                        const float* __restrict__ kp_w,        // [N, 64]
                        const int*   __restrict__ map_ids,     // [N] sorted
                        const float* __restrict__ emb,         // [V, 768]
                        const int*   __restrict__ batch_size_p,// [1]
                        float*       __restrict__ ret,         // [B, T, 768]
                        float*       __restrict__ mask,        // [B, T]
                        int N, int BT)
{
    const int tid = threadIdx.x;           // 0..191, one float4 column
    const int bid = blockIdx.x;
    const float4* __restrict__ emb4 = reinterpret_cast<const float4*>(emb);
    float4* __restrict__ ret4 = reinterpret_cast<float4*>(ret);

    if (bid < N) {
        // ---- one chunk: pool 64 token embeddings with normalized weights ----
        __shared__ int   s_ids[CHUNK_LEN];
        __shared__ float s_w[CHUNK_LEN];
        if (tid < CHUNK_LEN) {
            s_ids[tid] = input_ids[bid * CHUNK_LEN + tid];
            s_w[tid]   = kp_w[bid * CHUNK_LEN + tid];
        }
        __syncthreads();

        // weight sum (LDS broadcast reads, all lanes same address -> free)
        float wsum = 0.0f;
        #pragma unroll
        for (int l = 0; l < CHUNK_LEN; ++l) wsum += s_w[l];
        const float inv = 1.0f / wsum;

        // within-sample position: bid - lower_bound(map_ids, my_map)
        const int my_map = map_ids[bid];
        int lo = 0, hi = N;
        while (lo < hi) {
            int mid = (lo + hi) >> 1;
            if (map_ids[mid] < my_map) lo = mid + 1; else hi = mid;
        }
        const int pos = bid - lo;  // 0-based within sample

        const int B = *batch_size_p;
        const int T = BT / B;

        float4 acc = make_float4(0.f, 0.f, 0.f, 0.f);
        #pragma unroll 4
        for (int l = 0; l < CHUNK_LEN; ++l) {
            const int row = s_ids[l];
            const float4 v = emb4[(size_t)row * D4 + tid];  // coalesced 3KB/row
            const float wn = s_w[l] * inv;
            acc.x += v.x * wn;
            acc.y += v.y * wn;
            acc.z += v.z * wn;
            acc.w += v.w * wn;
        }
        ret4[((size_t)my_map * T + pos + 1) * D4 + tid] = acc;
        // mask for this slot is written by the sample block (full-row write)
    } else {
        // ---- per-sample block: CLS, SEP, zero ragged tail, full mask row ----
        const int b = bid - N;
        const int B = *batch_size_p;
        if (b >= B) return;
        const int T = BT / B;

        // count = upper_bound(b) - lower_bound(b) over sorted map_ids
        int lo = 0, hi = N;
        while (lo < hi) {
            int mid = (lo + hi) >> 1;
            if (map_ids[mid] < b) lo = mid + 1; else hi = mid;
        }
        const int lb = lo;
        lo = 0; hi = N;
        while (lo < hi) {
            int mid = (lo + hi) >> 1;
            if (map_ids[mid] <= b) lo = mid + 1; else hi = mid;
        }
        const int count = lo - lb;          // chunks for this sample

        // CLS at position 0
        ret4[((size_t)b * T + 0) * D4 + tid] = emb4[(size_t)CLS_IDX * D4 + tid];
        // SEP at position count+1
        ret4[((size_t)b * T + count + 1) * D4 + tid] = emb4[(size_t)SEP_IDX * D4 + tid];
        // zero tail rows [count+2, T)
        const float4 z = make_float4(0.f, 0.f, 0.f, 0.f);
        for (int r = count + 2; r < T; ++r) {
            ret4[((size_t)b * T + r) * D4 + tid] = z;
        }
        // full mask row: 1 for positions 0..count+1, else 0
        for (int j = tid; j < T; j += blockDim.x) {
            mask[(size_t)b * T + j] = (j <= count + 1) ? 1.0f : 0.0f;
        }
    }
}

extern "C" void kernel_launch(void* const* d_in, const int* in_sizes, int n_in,
                              void* d_out, int out_size, void* d_ws, size_t ws_size,
                              hipStream_t stream) {
    const int*   input_ids = (const int*)  d_in[0];
    const float* kp_w      = (const float*)d_in[1];
    const int*   map_ids   = (const int*)  d_in[2];
    const float* emb       = (const float*)d_in[3];
    const int*   bsz       = (const int*)  d_in[4];
    // d_in[5] (max_map_len) unused: T derived as BT/B on device.

    const int N  = in_sizes[0] / CHUNK_LEN;      // 4096 chunks
    const int BT = out_size / (DIM + 1);         // B*T (ret = BT*768, mask = BT)

    float* ret  = (float*)d_out;
    float* mask = ret + (size_t)BT * DIM;

    dim3 grid(N + MAX_B);
    dim3 block(D4);
    hipLaunchKernelGGL(chunk_embed_kernel, grid, block, 0, stream,
                       input_ids, kp_w, map_ids, emb, bsz, ret, mask, N, BT);
}

// Round 2
// 233.724 us; speedup vs baseline: 1.0066x; 1.0066x over previous
//
#include <hip/hip_runtime.h>

// ChunkEmbedding: embedding gather + normalized weighted pooling per chunk,
// ragged scatter into [B, T, D] with CLS/SEP rows + mask.
//
// R1: 8-deep rotating register prefetch in the gather loop. R0 counters showed
// latency-bound (VALUBusy 5.5%, hbm 40% peak, 0 bank conflicts): only ~4 loads
// in flight per lane. 8 float4 buffers double MLP; prefetch issued before the
// binary search so search latency overlaps pipeline fill.

constexpr int CHUNK_LEN = 64;
constexpr int DIM       = 768;
constexpr int D4        = DIM / 4;   // 192 float4 lanes per row
constexpr int CLS_IDX   = 101;
constexpr int SEP_IDX   = 102;
constexpr int MAX_B     = 256;       // guard blocks for sample work
constexpr int PF        = 8;         // prefetch depth (8 float4 = 32 VGPR)

__global__ __launch_bounds__(D4)
void chunk_embed_kernel(const int*   __restrict__ input_ids,   // [N, 64]
                        const float* __restrict__ kp_w,        // [N, 64]
                        const int*   __restrict__ map_ids,     // [N] sorted
                        const float* __restrict__ emb,         // [V, 768]
                        const int*   __restrict__ batch_size_p,// [1]
                        float*       __restrict__ ret,         // [B, T, 768]
                        float*       __restrict__ mask,        // [B, T]
                        int N, int BT)
{
    const int tid = threadIdx.x;           // 0..191, one float4 column
    const int bid = blockIdx.x;
    const float4* __restrict__ emb4 = reinterpret_cast<const float4*>(emb);
    float4* __restrict__ ret4 = reinterpret_cast<float4*>(ret);

    if (bid < N) {
        // ---- one chunk: pool 64 token embeddings with normalized weights ----
        __shared__ int   s_ids[CHUNK_LEN];
        __shared__ float s_w[CHUNK_LEN];
        if (tid < CHUNK_LEN) {
            s_ids[tid] = input_ids[bid * CHUNK_LEN + tid];
            s_w[tid]   = kp_w[bid * CHUNK_LEN + tid];
        }
        __syncthreads();

        // Issue the first PF row loads immediately: they fill the VMEM queue
        // while we do the (serial-latency) weight sum and binary search.
        float4 v[PF];
        #pragma unroll
        for (int j = 0; j < PF; ++j)
            v[j] = emb4[(size_t)s_ids[j] * D4 + tid];

        // weight sum (LDS broadcast reads — overlaps with loads above)
        float wsum = 0.0f;
        #pragma unroll
        for (int l = 0; l < CHUNK_LEN; ++l) wsum += s_w[l];
        const float inv = 1.0f / wsum;

        // within-sample position: bid - lower_bound(map_ids, my_map)
        const int my_map = map_ids[bid];
        int lo = 0, hi = N;
        while (lo < hi) {
            int mid = (lo + hi) >> 1;
            if (map_ids[mid] < my_map) lo = mid + 1; else hi = mid;
        }
        const int pos = bid - lo;  // 0-based within sample

        const int B = *batch_size_p;
        const int T = BT / B;

        // Rotating 8-deep pipeline: consume v[j], immediately re-issue the
        // load for row l+PF+j. Steady state keeps ~PF loads in flight.
        float4 acc = make_float4(0.f, 0.f, 0.f, 0.f);
        for (int l = 0; l < CHUNK_LEN; l += PF) {
            #pragma unroll
            for (int j = 0; j < PF; ++j) {
                const float  wn = s_w[l + j] * inv;
                const float4 x  = v[j];
                const int    nl = l + PF + j;
                if (nl < CHUNK_LEN)
                    v[j] = emb4[(size_t)s_ids[nl] * D4 + tid];
                acc.x += x.x * wn;
                acc.y += x.y * wn;
                acc.z += x.z * wn;
                acc.w += x.w * wn;
            }
        }
        ret4[((size_t)my_map * T + pos + 1) * D4 + tid] = acc;
        // mask for this slot is written by the sample block (full-row write)
    } else {
        // ---- per-sample block: CLS, SEP, zero ragged tail, full mask row ----
        const int b = bid - N;
        const int B = *batch_size_p;
        if (b >= B) return;
        const int T = BT / B;

        // count = upper_bound(b) - lower_bound(b) over sorted map_ids
        int lo = 0, hi = N;
        while (lo < hi) {
            int mid = (lo + hi) >> 1;
            if (map_ids[mid] < b) lo = mid + 1; else hi = mid;
        }
        const int lb = lo;
        lo = 0; hi = N;
        while (lo < hi) {
            int mid = (lo + hi) >> 1;
            if (map_ids[mid] <= b) lo = mid + 1; else hi = mid;
        }
        const int count = lo - lb;          // chunks for this sample

        // CLS at position 0
        ret4[((size_t)b * T + 0) * D4 + tid] = emb4[(size_t)CLS_IDX * D4 + tid];
        // SEP at position count+1
        ret4[((size_t)b * T + count + 1) * D4 + tid] = emb4[(size_t)SEP_IDX * D4 + tid];
        // zero tail rows [count+2, T)
        const float4 z = make_float4(0.f, 0.f, 0.f, 0.f);
        for (int r = count + 2; r < T; ++r) {
            ret4[((size_t)b * T + r) * D4 + tid] = z;
        }
        // full mask row: 1 for positions 0..count+1, else 0
        for (int j = tid; j < T; j += blockDim.x) {
            mask[(size_t)b * T + j] = (j <= count + 1) ? 1.0f : 0.0f;
        }
    }
}

extern "C" void kernel_launch(void* const* d_in, const int* in_sizes, int n_in,
                              void* d_out, int out_size, void* d_ws, size_t ws_size,
                              hipStream_t stream) {
    const int*   input_ids = (const int*)  d_in[0];
    const float* kp_w      = (const float*)d_in[1];
    const int*   map_ids   = (const int*)  d_in[2];
    const float* emb       = (const float*)d_in[3];
    const int*   bsz       = (const int*)  d_in[4];
    // d_in[5] (max_map_len) unused: T derived as BT/B on device.

    const int N  = in_sizes[0] / CHUNK_LEN;      // 4096 chunks
    const int BT = out_size / (DIM + 1);         // B*T (ret = BT*768, mask = BT)

    float* ret  = (float*)d_out;
    float* mask = ret + (size_t)BT * DIM;

    dim3 grid(N + MAX_B);
    dim3 block(D4);
    hipLaunchKernelGGL(chunk_embed_kernel, grid, block, 0, stream,
                       input_ids, kp_w, map_ids, emb, bsz, ret, mask, N, BT);
}